// Round 3
// baseline (140.379 us; speedup 1.0000x reference)
//
#include <hip/hip_runtime.h>
#include <stdint.h>
#include <stddef.h>

// GCCN: h1 = relu(x @ W1); h2 = relu(geo(h1, Wg1) + b1); res = geo(h2, Wg2) + b2; out = res/|res|
// geo(h, Wg)[n,o] = sum_b sum_i h[conn[n,b], i] * Wg[b,i,o]   (gathered GEMM, K = 80*64)
// Split-K over bins: 4 chunks x 20 bins -> f32 partials -> finalize kernels.

typedef __attribute__((ext_vector_type(8))) short bf16x8;
typedef __attribute__((ext_vector_type(4))) float f32x4;

#define BINS 80
#define SPLITK 4
#define BPC 20           // bins per chunk = BINS / SPLITK

static __device__ __forceinline__ unsigned short f2bf(float f) {
  union { float f; unsigned int u; } c; c.f = f;
  unsigned int u = c.u;
  return (unsigned short)((u + 0x7FFFu + ((u >> 16) & 1u)) >> 16);
}

// ---------------- linear_1: h1[v][64] = relu(x[v][0:16] @ W1) as bf16 ----------------
__global__ __launch_bounds__(256) void k_lin1(const float* __restrict__ x,
                                              const float* __restrict__ W1,
                                              unsigned short* __restrict__ h1b, int n) {
  __shared__ float w1s[16 * 64];
  int tid = threadIdx.x;
  for (int i = tid; i < 16 * 64; i += 256) w1s[i] = W1[i];
  __syncthreads();
  int v = blockIdx.x * 256 + tid;
  if (v >= n) return;
  const float4* xp = (const float4*)(x + (size_t)v * 16);
  float4 x0 = xp[0], x1 = xp[1], x2 = xp[2], x3 = xp[3];
  float xr[16] = {x0.x, x0.y, x0.z, x0.w, x1.x, x1.y, x1.z, x1.w,
                  x2.x, x2.y, x2.z, x2.w, x3.x, x3.y, x3.z, x3.w};
  float acc[64];
#pragma unroll
  for (int o = 0; o < 64; ++o) acc[o] = 0.f;
#pragma unroll
  for (int i = 0; i < 16; ++i) {
    float xi = xr[i];
#pragma unroll
    for (int o = 0; o < 64; ++o) acc[o] = fmaf(xi, w1s[i * 64 + o], acc[o]);
  }
  unsigned short* hr = h1b + (size_t)v * 64;
#pragma unroll
  for (int o8 = 0; o8 < 8; ++o8) {
    bf16x8 pack;
#pragma unroll
    for (int j = 0; j < 8; ++j) pack[j] = (short)f2bf(fmaxf(acc[o8 * 8 + j], 0.f));
    *(bf16x8*)(hr + o8 * 8) = pack;
  }
}

// ------ weight image: Wg[b][i][o] f32 -> img[b] rows o (128B of bf16 i), XOR-swizzled ------
// byte(o,i) = (o*128 + i*2) ^ ((o&7)<<4)
__global__ __launch_bounds__(256) void k_wimg(const float* __restrict__ Wg,
                                              unsigned char* __restrict__ img,
                                              int O, int total) {
  int t = blockIdx.x * 256 + threadIdx.x;
  if (t >= total) return;                 // total = 80 * O * 8 chunk tasks
  int c = t & 7;                          // 16B chunk within row (8 i-values)
  int o = (t >> 3) % O;
  int b = t / (O * 8);
  int boff = (o * 128 + c * 16) ^ ((o & 7) << 4);
  bf16x8 pack;
#pragma unroll
  for (int j = 0; j < 8; ++j)
    pack[j] = (short)f2bf(Wg[(size_t)(b * 64 + c * 8 + j) * O + o]);
  *(bf16x8*)(img + (size_t)b * (O * 128) + boff) = pack;
}

// ---------------- geodesic layer, split-K chunk: f32 partials ----------------
// grid (gb, SPLITK); block 256 = 4 waves; wave w owns rows [v0 + w*16, +16), all O cols.
// chunk = blockIdx.y handles bins [chunk*BPC, +BPC).
template <int OT>
__global__ __launch_bounds__(256) void k_geo_sk(const unsigned short* __restrict__ hin,
                                                const unsigned char* __restrict__ wimg,
                                                const int* __restrict__ conn,
                                                float* __restrict__ part, int n) {
  constexpr int TILEB = OT * 16 * 128;   // bytes per bin weight tile (8KB / 4KB)
  __shared__ int conn_s[64 * (BPC + 1)];
  __shared__ alignas(16) unsigned char wg_s[2][TILEB];

  const int tid = threadIdx.x;
  const int lane = tid & 63;
  const int wave = tid >> 6;
  const int ln15 = lane & 15;
  const int lq = lane >> 4;              // 0..3
  const int v0 = blockIdx.x * 64;
  const int chunk = blockIdx.y;
  const int bin0 = chunk * BPC;

  // stage this chunk's conn slice for the 64 vertices (clamped for tail block)
  for (int idx = tid; idx < 64 * BPC; idx += 256) {
    int v = idx / BPC;
    int c = idx - v * BPC;
    int vv = v0 + v;
    if (vv > n - 1) vv = n - 1;
    conn_s[v * (BPC + 1) + c] = conn[(size_t)vv * BINS + bin0 + c];
  }

  auto stage = [&](int bin, int buf) {
    const unsigned char* src = wimg + (size_t)bin * TILEB + wave * (TILEB / 4) + lane * 16;
    unsigned char* dst = &wg_s[buf][wave * (TILEB / 4)];
#pragma unroll
    for (int i = 0; i < TILEB / 4096; ++i) {
      __builtin_amdgcn_global_load_lds(
          (const __attribute__((address_space(1))) unsigned int*)(const void*)(src + i * 1024),
          (__attribute__((address_space(3))) unsigned int*)(void*)(dst + i * 1024),
          16, 0, 0);
    }
  };

  // per-lane swizzled B-fragment byte offsets (constant across bins)
  int boffs[OT][2];
#pragma unroll
  for (int ot = 0; ot < OT; ++ot)
#pragma unroll
    for (int s = 0; s < 2; ++s) {
      int o = ot * 16 + ln15;
      boffs[ot][s] = (o * 128 + s * 64 + lq * 16) ^ ((o & 7) << 4);
    }

  f32x4 acc[OT];
#pragma unroll
  for (int ot = 0; ot < OT; ++ot) acc[ot] = (f32x4){0.f, 0.f, 0.f, 0.f};

  stage(bin0, 0);
  __syncthreads();   // conn_s ready + wg_s[0] landed (barrier drains vmcnt)

  const int crow = (wave * 16 + ln15) * (BPC + 1);
  const int koff = lq * 8;

  // preload A for first bin
  bf16x8 a0, a1;
  {
    int cidx = conn_s[crow];
    const unsigned short* arow = hin + (size_t)cidx * 64 + koff;
    a0 = *(const bf16x8*)(arow);
    a1 = *(const bf16x8*)(arow + 32);
  }

  for (int cb = 0; cb < BPC; ++cb) {
    int cur = cb & 1;
    bf16x8 na0 = a0, na1 = a1;
    if (cb + 1 < BPC) {
      stage(bin0 + cb + 1, cur ^ 1);
      int nc = conn_s[crow + cb + 1];
      const unsigned short* arow = hin + (size_t)nc * 64 + koff;
      na0 = *(const bf16x8*)(arow);
      na1 = *(const bf16x8*)(arow + 32);
    }

    const unsigned char* wb = wg_s[cur];
#pragma unroll
    for (int ot = 0; ot < OT; ++ot) {
      bf16x8 b0 = *(const bf16x8*)(wb + boffs[ot][0]);
      bf16x8 b1 = *(const bf16x8*)(wb + boffs[ot][1]);
      acc[ot] = __builtin_amdgcn_mfma_f32_16x16x32_bf16(a0, b0, acc[ot], 0, 0, 0);
      acc[ot] = __builtin_amdgcn_mfma_f32_16x16x32_bf16(a1, b1, acc[ot], 0, 0, 0);
    }
    __syncthreads();  // next stage landed; all waves done reading wg_s[cur]
    a0 = na0; a1 = na1;
  }

  // write f32 partials: part[(chunk*n + v)*O + o]; C/D layout col=lane&15, row=lq*4+r
  constexpr int O = OT * 16;
  float* pbase = part + (size_t)chunk * n * O;
#pragma unroll
  for (int ot = 0; ot < OT; ++ot) {
#pragma unroll
    for (int r = 0; r < 4; ++r) {
      int v = v0 + wave * 16 + lq * 4 + r;
      if (v < n) pbase[(size_t)v * O + ot * 16 + ln15] = acc[ot][r];
    }
  }
}

// ---------------- finalize GC1: sum 4 partials + bias, relu, bf16 ----------------
__global__ __launch_bounds__(256) void k_fin1(const float* __restrict__ part,
                                              const float* __restrict__ bias,
                                              unsigned short* __restrict__ out, int n) {
  int t = blockIdx.x * 256 + threadIdx.x;
  int total = n * 16;                     // groups of 4 outputs
  if (t >= total) return;
  int base = t * 4;
  int o = base & 63;
  size_t stride = (size_t)n * 64;
  const float* p = part + base;
  float4 s = *(const float4*)(p);
#pragma unroll
  for (int c = 1; c < SPLITK; ++c) {
    float4 q = *(const float4*)(p + c * stride);
    s.x += q.x; s.y += q.y; s.z += q.z; s.w += q.w;
  }
  float4 b4 = *(const float4*)(bias + o);
  ushort4 pack;
  pack.x = f2bf(fmaxf(s.x + b4.x, 0.f));
  pack.y = f2bf(fmaxf(s.y + b4.y, 0.f));
  pack.z = f2bf(fmaxf(s.z + b4.z, 0.f));
  pack.w = f2bf(fmaxf(s.w + b4.w, 0.f));
  *(ushort4*)(out + base) = pack;
}

// ---------------- finalize GC2: sum 4 partials + bias, normalize ----------------
__global__ __launch_bounds__(256) void k_fin2(const float* __restrict__ part,
                                              const float* __restrict__ bias,
                                              float* __restrict__ out, int n) {
  int v = blockIdx.x * 16 + (threadIdx.x >> 4);
  int o = threadIdx.x & 15;
  if (v >= n) return;
  size_t stride = (size_t)n * 32;
  const float* p = part + (size_t)v * 32 + o;
  float a = 0.f, b = 0.f;
#pragma unroll
  for (int c = 0; c < SPLITK; ++c) {
    a += p[c * stride];
    b += p[c * stride + 16];
  }
  a += bias[o];
  b += bias[o + 16];
  float ss = a * a + b * b;
  ss += __shfl_xor(ss, 1);
  ss += __shfl_xor(ss, 2);
  ss += __shfl_xor(ss, 4);
  ss += __shfl_xor(ss, 8);
  float inv = 1.0f / sqrtf(ss);
  out[(size_t)v * 32 + o] = a * inv;
  out[(size_t)v * 32 + 16 + o] = b * inv;
}

extern "C" void kernel_launch(void* const* d_in, const int* in_sizes, int n_in,
                              void* d_out, int out_size, void* d_ws, size_t ws_size,
                              hipStream_t stream) {
  const float* x   = (const float*)d_in[0];
  const float* W1  = (const float*)d_in[1];
  const float* Wg1 = (const float*)d_in[2];
  const float* b1  = (const float*)d_in[3];
  const float* Wg2 = (const float*)d_in[4];
  const float* b2  = (const float*)d_in[5];
  const int*  conn = (const int*)d_in[6];
  int n = in_sizes[0] / 16;

  unsigned char* ws = (unsigned char*)d_ws;
  size_t hb = ((size_t)n * 64 * 2 + 255) & ~(size_t)255;   // bf16 h table bytes
  unsigned short* h1b = (unsigned short*)(ws);
  unsigned short* h2b = (unsigned short*)(ws + hb);
  unsigned char*  w1i = ws + 2 * hb;                        // 80 * 8192
  unsigned char*  w2i = ws + 2 * hb + 80 * 8192;            // 80 * 4096
  float* part = (float*)(ws + 2 * hb + 80 * 8192 + 80 * 4096);  // SPLITK*n*64 f32 (layer2 aliases)

  k_wimg<<<(80 * 64 * 8 + 255) / 256, 256, 0, stream>>>(Wg1, w1i, 64, 80 * 64 * 8);
  k_wimg<<<(80 * 32 * 8 + 255) / 256, 256, 0, stream>>>(Wg2, w2i, 32, 80 * 32 * 8);
  k_lin1<<<(n + 255) / 256, 256, 0, stream>>>(x, W1, h1b, n);

  int gb = (n + 63) / 64;
  k_geo_sk<4><<<dim3(gb, SPLITK), 256, 0, stream>>>(h1b, w1i, conn, part, n);
  k_fin1<<<(n * 16 + 255) / 256, 256, 0, stream>>>(part, b1, h2b, n);
  k_geo_sk<2><<<dim3(gb, SPLITK), 256, 0, stream>>>(h2b, w2i, conn, part, n);
  k_fin2<<<(n + 15) / 16, 256, 0, stream>>>(part, b2, (float*)d_out, n);
}

// Round 4
// 136.691 us; speedup vs baseline: 1.0270x; 1.0270x over previous
//
#include <hip/hip_runtime.h>
#include <stdint.h>
#include <stddef.h>

// GCCN: h1 = relu(x @ W1); h2 = relu(geo(h1, Wg1) + b1); res = geo(h2, Wg2) + b2; out = res/|res|
// geo(h, Wg)[n,o] = sum_b sum_i h[conn[n,b], i] * Wg[b,i,o]   (gathered GEMM, K = 80*64)
// Split-K over bins (4 x 20) -> f32 partials -> finalize kernels.
// k_geo_sk uses a T3/T4-style deep pipeline: 4 LDS weight buffers staged 2 bins
// ahead via global_load_lds, A-gathers 2 bins ahead in registers, counted
// s_waitcnt vmcnt(N) + raw s_barrier (never drain to 0 in the main loop).

typedef __attribute__((ext_vector_type(8))) short bf16x8;
typedef __attribute__((ext_vector_type(4))) float f32x4;

#define BINS 80
#define SPLITK 4
#define BPC 20           // bins per chunk
#define MROWS 128        // rows per block (4 waves x 2 m-tiles x 16)

static __device__ __forceinline__ unsigned short f2bf(float f) {
  union { float f; unsigned int u; } c; c.f = f;
  unsigned int u = c.u;
  return (unsigned short)((u + 0x7FFFu + ((u >> 16) & 1u)) >> 16);
}

template <int N> static __device__ __forceinline__ void wait_vmcnt() {
  if constexpr (N == 12)      asm volatile("s_waitcnt vmcnt(12)" ::: "memory");
  else if constexpr (N == 10) asm volatile("s_waitcnt vmcnt(10)" ::: "memory");
  else if constexpr (N == 6)  asm volatile("s_waitcnt vmcnt(6)" ::: "memory");
  else if constexpr (N == 5)  asm volatile("s_waitcnt vmcnt(5)" ::: "memory");
  else                        asm volatile("s_waitcnt vmcnt(0)" ::: "memory");
}

// ---------------- linear_1: h1[v][64] = relu(x[v][0:16] @ W1) as bf16 ----------------
__global__ __launch_bounds__(256) void k_lin1(const float* __restrict__ x,
                                              const float* __restrict__ W1,
                                              unsigned short* __restrict__ h1b, int n) {
  __shared__ float w1s[16 * 64];
  int tid = threadIdx.x;
  for (int i = tid; i < 16 * 64; i += 256) w1s[i] = W1[i];
  __syncthreads();
  int v = blockIdx.x * 256 + tid;
  if (v >= n) return;
  const float4* xp = (const float4*)(x + (size_t)v * 16);
  float4 x0 = xp[0], x1 = xp[1], x2 = xp[2], x3 = xp[3];
  float xr[16] = {x0.x, x0.y, x0.z, x0.w, x1.x, x1.y, x1.z, x1.w,
                  x2.x, x2.y, x2.z, x2.w, x3.x, x3.y, x3.z, x3.w};
  float acc[64];
#pragma unroll
  for (int o = 0; o < 64; ++o) acc[o] = 0.f;
#pragma unroll
  for (int i = 0; i < 16; ++i) {
    float xi = xr[i];
#pragma unroll
    for (int o = 0; o < 64; ++o) acc[o] = fmaf(xi, w1s[i * 64 + o], acc[o]);
  }
  unsigned short* hr = h1b + (size_t)v * 64;
#pragma unroll
  for (int o8 = 0; o8 < 8; ++o8) {
    bf16x8 pack;
#pragma unroll
    for (int j = 0; j < 8; ++j) pack[j] = (short)f2bf(fmaxf(acc[o8 * 8 + j], 0.f));
    *(bf16x8*)(hr + o8 * 8) = pack;
  }
}

// ------ weight image: Wg[b][i][o] f32 -> img[b] rows o (128B of bf16 i), XOR-swizzled ------
// byte(o,i) = (o*128 + i*2) ^ ((o&7)<<4)
__global__ __launch_bounds__(256) void k_wimg(const float* __restrict__ Wg,
                                              unsigned char* __restrict__ img,
                                              int O, int total) {
  int t = blockIdx.x * 256 + threadIdx.x;
  if (t >= total) return;                 // total = 80 * O * 8 chunk tasks
  int c = t & 7;                          // 16B chunk within row (8 i-values)
  int o = (t >> 3) % O;
  int b = t / (O * 8);
  int boff = (o * 128 + c * 16) ^ ((o & 7) << 4);
  bf16x8 pack;
#pragma unroll
  for (int j = 0; j < 8; ++j)
    pack[j] = (short)f2bf(Wg[(size_t)(b * 64 + c * 8 + j) * O + o]);
  *(bf16x8*)(img + (size_t)b * (O * 128) + boff) = pack;
}

// ---------------- geodesic layer, split-K chunk: deep-pipelined ----------------
// grid (gb, SPLITK); block 256 = 4 waves; wave w owns rows [v0 + w*32, +32) (2 m-tiles).
template <int OT>
__global__ __launch_bounds__(256, 3) void k_geo_sk(const unsigned short* __restrict__ hin,
                                                   const unsigned char* __restrict__ wimg,
                                                   const int* __restrict__ conn,
                                                   float* __restrict__ part, int n) {
  constexpr int TILEB = OT * 16 * 128;        // bytes per bin weight tile (8KB / 4KB)
  constexpr int SINSTS = TILEB / 4096;        // global_load_lds insts per wave per stage
  constexpr int IPI = 4 + SINSTS;             // vmem ops issued per pipeline step

  __shared__ int conn_s[MROWS * (BPC + 1)];
  __shared__ alignas(16) unsigned char wg_s[4][TILEB];

  const int tid = threadIdx.x;
  const int lane = tid & 63;
  const int wave = tid >> 6;
  const int ln15 = lane & 15;
  const int lq = lane >> 4;                   // 0..3
  const int v0 = blockIdx.x * MROWS;
  const int chunk = blockIdx.y;
  const int bin0 = chunk * BPC;

  // stage this chunk's conn slice (clamped for tail block)
  for (int idx = tid; idx < MROWS * BPC; idx += 256) {
    int v = idx / BPC;
    int c = idx - v * BPC;
    int vv = v0 + v;
    if (vv > n - 1) vv = n - 1;
    conn_s[v * (BPC + 1) + c] = conn[(size_t)vv * BINS + bin0 + c];
  }

  // per-lane swizzled B-fragment byte offsets (constant across bins)
  int boffs[OT][2];
#pragma unroll
  for (int ot = 0; ot < OT; ++ot)
#pragma unroll
    for (int s = 0; s < 2; ++s) {
      int o = ot * 16 + ln15;
      boffs[ot][s] = (o * 128 + s * 64 + lq * 16) ^ ((o & 7) << 4);
    }

  const int koff = lq * 8;
  bf16x8 As[3][2][2];                         // 3 rotating in-flight A sets
  f32x4 acc[2][OT];
#pragma unroll
  for (int mt = 0; mt < 2; ++mt)
#pragma unroll
    for (int ot = 0; ot < OT; ++ot) acc[mt][ot] = (f32x4){0.f, 0.f, 0.f, 0.f};

  // issue(j): gather A(j) into As[j%3] (4 vmem), then stage Wg tile j into wg_s[j%4]
  auto issue = [&](int j) {
#pragma unroll
    for (int mt = 0; mt < 2; ++mt) {
      int cidx = conn_s[(wave * 32 + mt * 16 + ln15) * (BPC + 1) + j];
      const unsigned short* arow = hin + (size_t)cidx * 64 + koff;
      As[j % 3][mt][0] = *(const bf16x8*)(arow);
      As[j % 3][mt][1] = *(const bf16x8*)(arow + 32);
    }
    __builtin_amdgcn_sched_barrier(0);
    const unsigned char* src =
        wimg + (size_t)(bin0 + j) * TILEB + wave * (TILEB / 4) + lane * 16;
    unsigned char* dst = &wg_s[j & 3][wave * (TILEB / 4)];
#pragma unroll
    for (int i = 0; i < SINSTS; ++i) {
      __builtin_amdgcn_global_load_lds(
          (const __attribute__((address_space(1))) unsigned int*)(const void*)(src + i * 1024),
          (__attribute__((address_space(3))) unsigned int*)(void*)(dst + i * 1024),
          16, 0, 0);
    }
    __builtin_amdgcn_sched_barrier(0);
  };

  __syncthreads();          // conn_s ready (full drain once, outside the hot loop)
  issue(0);
  issue(1);

#pragma unroll
  for (int cb = 0; cb < BPC; ++cb) {
    if (cb + 2 < BPC) issue(cb + 2);
    // wait for A(cb) + stage(cb): both issued 2 steps ago -> allow the newer
    // steps' IPI*2 ops to stay in flight. Tail steps issue less -> tighter N.
    const int nafter = IPI * ((cb + 1 < BPC ? 1 : 0) + (cb + 2 < BPC ? 1 : 0));
    if (nafter == 2 * IPI)      wait_vmcnt<2 * IPI>();
    else if (nafter == IPI)     wait_vmcnt<IPI>();
    else                        wait_vmcnt<0>();
    __builtin_amdgcn_s_barrier();            // all waves' stage(cb) retired
    __builtin_amdgcn_sched_barrier(0);       // rule #18: no hoisting above barrier

    const unsigned char* wb = wg_s[cb & 3];
#pragma unroll
    for (int ot = 0; ot < OT; ++ot) {
      bf16x8 b0 = *(const bf16x8*)(wb + boffs[ot][0]);
      bf16x8 b1 = *(const bf16x8*)(wb + boffs[ot][1]);
#pragma unroll
      for (int mt = 0; mt < 2; ++mt) {
        acc[mt][ot] = __builtin_amdgcn_mfma_f32_16x16x32_bf16(As[cb % 3][mt][0], b0,
                                                              acc[mt][ot], 0, 0, 0);
        acc[mt][ot] = __builtin_amdgcn_mfma_f32_16x16x32_bf16(As[cb % 3][mt][1], b1,
                                                              acc[mt][ot], 0, 0, 0);
      }
    }
  }

  // write f32 partials: part[(chunk*n + v)*O + o]; C/D layout col=lane&15, row=lq*4+r
  constexpr int O = OT * 16;
  float* pbase = part + (size_t)chunk * n * O;
#pragma unroll
  for (int mt = 0; mt < 2; ++mt)
#pragma unroll
    for (int ot = 0; ot < OT; ++ot)
#pragma unroll
      for (int r = 0; r < 4; ++r) {
        int v = v0 + wave * 32 + mt * 16 + lq * 4 + r;
        if (v < n) pbase[(size_t)v * O + ot * 16 + ln15] = acc[mt][ot][r];
      }
}

// ---------------- finalize GC1: sum 4 partials + bias, relu, bf16 ----------------
__global__ __launch_bounds__(256) void k_fin1(const float* __restrict__ part,
                                              const float* __restrict__ bias,
                                              unsigned short* __restrict__ out, int n) {
  int t = blockIdx.x * 256 + threadIdx.x;
  int total = n * 16;                     // groups of 4 outputs
  if (t >= total) return;
  int base = t * 4;
  int o = base & 63;
  size_t stride = (size_t)n * 64;
  const float* p = part + base;
  float4 s = *(const float4*)(p);
#pragma unroll
  for (int c = 1; c < SPLITK; ++c) {
    float4 q = *(const float4*)(p + c * stride);
    s.x += q.x; s.y += q.y; s.z += q.z; s.w += q.w;
  }
  float4 b4 = *(const float4*)(bias + o);
  ushort4 pack;
  pack.x = f2bf(fmaxf(s.x + b4.x, 0.f));
  pack.y = f2bf(fmaxf(s.y + b4.y, 0.f));
  pack.z = f2bf(fmaxf(s.z + b4.z, 0.f));
  pack.w = f2bf(fmaxf(s.w + b4.w, 0.f));
  *(ushort4*)(out + base) = pack;
}

// ---------------- finalize GC2: sum 4 partials + bias, normalize ----------------
__global__ __launch_bounds__(256) void k_fin2(const float* __restrict__ part,
                                              const float* __restrict__ bias,
                                              float* __restrict__ out, int n) {
  int v = blockIdx.x * 16 + (threadIdx.x >> 4);
  int o = threadIdx.x & 15;
  if (v >= n) return;
  size_t stride = (size_t)n * 32;
  const float* p = part + (size_t)v * 32 + o;
  float a = 0.f, b = 0.f;
#pragma unroll
  for (int c = 0; c < SPLITK; ++c) {
    a += p[c * stride];
    b += p[c * stride + 16];
  }
  a += bias[o];
  b += bias[o + 16];
  float ss = a * a + b * b;
  ss += __shfl_xor(ss, 1);
  ss += __shfl_xor(ss, 2);
  ss += __shfl_xor(ss, 4);
  ss += __shfl_xor(ss, 8);
  float inv = 1.0f / sqrtf(ss);
  out[(size_t)v * 32 + o] = a * inv;
  out[(size_t)v * 32 + 16 + o] = b * inv;
}

extern "C" void kernel_launch(void* const* d_in, const int* in_sizes, int n_in,
                              void* d_out, int out_size, void* d_ws, size_t ws_size,
                              hipStream_t stream) {
  const float* x   = (const float*)d_in[0];
  const float* W1  = (const float*)d_in[1];
  const float* Wg1 = (const float*)d_in[2];
  const float* b1  = (const float*)d_in[3];
  const float* Wg2 = (const float*)d_in[4];
  const float* b2  = (const float*)d_in[5];
  const int*  conn = (const int*)d_in[6];
  int n = in_sizes[0] / 16;

  unsigned char* ws = (unsigned char*)d_ws;
  size_t hb = ((size_t)n * 64 * 2 + 255) & ~(size_t)255;   // bf16 h table bytes
  unsigned short* h1b = (unsigned short*)(ws);
  unsigned short* h2b = (unsigned short*)(ws + hb);
  unsigned char*  w1i = ws + 2 * hb;                        // 80 * 8192
  unsigned char*  w2i = ws + 2 * hb + 80 * 8192;            // 80 * 4096
  float* part = (float*)(ws + 2 * hb + 80 * 8192 + 80 * 4096);  // SPLITK*n*64 f32

  k_wimg<<<(80 * 64 * 8 + 255) / 256, 256, 0, stream>>>(Wg1, w1i, 64, 80 * 64 * 8);
  k_wimg<<<(80 * 32 * 8 + 255) / 256, 256, 0, stream>>>(Wg2, w2i, 32, 80 * 32 * 8);
  k_lin1<<<(n + 255) / 256, 256, 0, stream>>>(x, W1, h1b, n);

  int gb = (n + MROWS - 1) / MROWS;
  k_geo_sk<4><<<dim3(gb, SPLITK), 256, 0, stream>>>(h1b, w1i, conn, part, n);
  k_fin1<<<(n * 16 + 255) / 256, 256, 0, stream>>>(part, b1, h2b, n);
  k_geo_sk<2><<<dim3(gb, SPLITK), 256, 0, stream>>>(h2b, w2i, conn, part, n);
  k_fin2<<<(n + 15) / 16, 256, 0, stream>>>(part, b2, (float*)d_out, n);
}